// Round 2
// baseline (460.124 us; speedup 1.0000x reference)
//
#include <hip/hip_runtime.h>

// SpatialCorrelationSampler: out[b,(dy+4)*9+(dx+4),y,x] =
//   sum_c f0[b,c,y,x]*f1[b,c,y+dy,x+dx], dy,dx in [-4,4], OOB=0.
// B=4 C=256 H=96 W=160 -> out (4,81,96,160) fp32.
//
// R2: fix R1's accumulator spill (VGPR_Count=68 < 72 accs -> scratch-bound,
// 209us). Tile 16x16, RX=4 -> 36 accs, ~90 VGPR live set; launch_bounds(576,5)
// caps at 102 so 2 blocks (18 waves) fit per CU. Grid 240 tiles x 4 C-split
// = 960 blocks. Staging = exactly one float4/thread/stage (no private arrays).
// LDS row stride 28 -> balanced 8 dword/bank b128 reads.

#define Bn 4
#define Cn 256
#define Hn 96
#define Wn 160
#define HWn (Hn * Wn)
#define NP 81
#define TY 16
#define TX 16
#define NCSPLIT 4
#define CPB (Cn / NCSPLIT)   // 64 channels per block
#define CCH 4                // channels staged per round
#define NSTAGE (CPB / CCH)   // 16
#define WROWS (TY + 8)       // 24
#define WCOLS (TX + 8)       // 24
#define SEGS (WCOLS / 4)     // 6 float4 segments per row
#define LROW 28              // padded LDS row stride (floats)
#define F1C (WROWS * LROW)   // 672 floats per staged channel
#define NT 576               // 9 waves; wave w owns dy = w-4

__global__ __launch_bounds__(NT, 5) void corr_kernel(const float* __restrict__ f0,
                                                     const float* __restrict__ f1,
                                                     float* __restrict__ out) {
    __shared__ __align__(16) float lds[CCH * F1C];  // 10752 B

    const int tid  = threadIdx.x;
    const int wave = tid >> 6;      // 0..8 (dy = wave-4)
    const int lane = tid & 63;
    const int r    = lane >> 2;     // 0..15 tile row
    const int g    = lane & 3;      // 0..3  col group of 4 px

    const int tile = blockIdx.x;    // 0..239
    const int b    = tile / 60;
    const int rem  = tile % 60;
    const int ty   = rem / 10;
    const int tx   = rem - ty * 10;
    const int y0   = ty * TY;
    const int x0   = tx * TX;
    const int c0   = blockIdx.y * CPB;

    // ---- staging assignment: exactly one float4 copy per thread per stage
    // tid -> (cc, rr, seg): cc = tid/144, rr = (tid%144)/6, seg = tid%6
    const int scc  = tid / (WROWS * SEGS);
    const int srm  = tid - scc * (WROWS * SEGS);
    const int srr  = srm / SEGS;
    const int sseg = srm - srr * SEGS;
    const int sgy  = y0 - 4 + srr;
    const int sgx  = x0 - 4 + sseg * 4;          // mult of 4; seg all-in or all-out
    const bool sval = (sgy >= 0) && (sgy < Hn) && (sgx >= 0) && (sgx < Wn);
    const int slidx = (scc * F1C + srr * LROW + sseg * 4) >> 2;
    const int sgidx = sval ? ((((b * Cn + c0 + scc) * Hn + sgy) * Wn + sgx) >> 2) : 0;

    float acc[9][4];
#pragma unroll
    for (int i = 0; i < 9; ++i)
#pragma unroll
        for (int j = 0; j < 4; ++j) acc[i][j] = 0.f;

    const int f0base = ((b * Cn + c0) * Hn + y0 + r) * Wn + x0 + g * 4;
    const float4* __restrict__ f1v = (const float4*)f1;
    float4* lv = (float4*)lds;

    for (int stage = 0; stage < NSTAGE; ++stage) {
        __syncthreads();  // previous compute done reading LDS
        {
            float4 v = make_float4(0.f, 0.f, 0.f, 0.f);
            if (sval) v = f1v[sgidx + stage * (CCH * HWn / 4)];
            lv[slidx] = v;
        }
        __syncthreads();

#pragma unroll
        for (int cc = 0; cc < CCH; ++cc) {
            const float* f0p = f0 + f0base + (stage * CCH + cc) * HWn;
            float4 a = *(const float4*)(f0p);
            const float* wr = &lds[cc * F1C + (r + wave) * LROW + g * 4];
            float4 w0 = *(const float4*)(wr);
            float4 w1 = *(const float4*)(wr + 4);
            float4 w2 = *(const float4*)(wr + 8);
            float av[4]  = {a.x, a.y, a.z, a.w};
            float wv[12] = {w0.x, w0.y, w0.z, w0.w, w1.x, w1.y, w1.z, w1.w,
                            w2.x, w2.y, w2.z, w2.w};
#pragma unroll
            for (int dx = 0; dx < 9; ++dx)
#pragma unroll
                for (int rx = 0; rx < 4; ++rx)
                    acc[dx][rx] = fmaf(av[rx], wv[rx + dx], acc[dx][rx]);
        }
    }

    // epilogue: exclusive (b,dy-plane,tile) per wave except C-split -> atomicAdd
    const int orow = ((b * NP + wave * 9) * Hn + y0 + r) * Wn + x0 + g * 4;
#pragma unroll
    for (int dx = 0; dx < 9; ++dx) {
        float* o = out + orow + dx * (Hn * Wn);
#pragma unroll
        for (int rx = 0; rx < 4; ++rx) atomicAdd(o + rx, acc[dx][rx]);
    }
}

__global__ void zero_kernel(float4* __restrict__ o, int n4) {
    int i = blockIdx.x * blockDim.x + threadIdx.x;
    if (i < n4) o[i] = make_float4(0.f, 0.f, 0.f, 0.f);
}

extern "C" void kernel_launch(void* const* d_in, const int* in_sizes, int n_in,
                              void* d_out, int out_size, void* d_ws, size_t ws_size,
                              hipStream_t stream) {
    const float* f0 = (const float*)d_in[0];
    const float* f1 = (const float*)d_in[1];
    float* out = (float*)d_out;

    const int n4 = Bn * NP * Hn * Wn / 4;  // 1,244,160 float4s (19.9 MB)
    zero_kernel<<<(n4 + 255) / 256, 256, 0, stream>>>((float4*)out, n4);
    corr_kernel<<<dim3(240, NCSPLIT), NT, 0, stream>>>(f0, f1, out);
}

// Round 3
// 195.654 us; speedup vs baseline: 2.3517x; 2.3517x over previous
//
#include <hip/hip_runtime.h>

// SpatialCorrelationSampler: out[b,(dy+4)*9+(dx+4),y,x] =
//   sum_c f0[b,c,y,x]*f1[b,c,y+dy,x+dx], dy,dx in [-4,4], OOB=0.
// B=4 C=256 H=96 W=160 -> out (4,81,96,160) fp32.
//
// R3: R2 post-mortem showed no spill traffic (FETCH==ideal) but 93% stall:
// 19.9M atomicAdds with 4x HBM RMW turnover (WRITE 311MB) + barrier-serialized
// 64-stage loop with ~1 block/CU and zero latency hiding.
//   -> NCSPLIT=1: block reduces ALL 256 ch for its 16x16 tile; plain float4
//      stores, no atomics, no zero-kernel. WRITE -> 20 MB.
//   -> Register prefetch + LDS double-buffer: stage s+1 f1/f0 loads issued
//      after the single per-stage barrier, in flight during stage-s compute.
//   -> launch_bounds(576,2): 256-VGPR cap, keep ~110-reg live set in VGPRs.

#define Bn 4
#define Cn 256
#define Hn 96
#define Wn 160
#define HWn (Hn * Wn)
#define NP 81
#define TY 16
#define TX 16
#define CCH 4                 // channels staged per stage
#define NSTAGE (Cn / CCH)     // 64
#define WROWS (TY + 8)        // 24
#define WCOLS (TX + 8)        // 24
#define SEGS (WCOLS / 4)      // 6 float4 segments per row
#define LROW 28               // padded LDS row stride (floats): 2-way-max bank aliasing
#define F1C (WROWS * LROW)    // 672 floats per staged channel
#define NT 576                // 9 waves; wave w owns dy = w-4
#define F1CHUNK4 (CCH * HWn / 4)  // float4 stride between stages in f1

__global__ __launch_bounds__(NT, 2) void corr_kernel(const float* __restrict__ f0,
                                                     const float* __restrict__ f1,
                                                     float* __restrict__ out) {
    __shared__ __align__(16) float lds[2 * CCH * F1C];  // 21504 B, double-buffered

    const int tid  = threadIdx.x;
    const int wave = tid >> 6;      // 0..8 (dy = wave-4)
    const int lane = tid & 63;
    const int r    = lane >> 2;     // 0..15 tile row
    const int g    = lane & 3;      // 0..3  col group of 4 px

    const int tile = blockIdx.x;    // 0..239
    const int b    = tile / 60;
    const int rem  = tile % 60;
    const int ty   = rem / 10;
    const int tx   = rem - ty * 10;
    const int y0   = ty * TY;
    const int x0   = tx * TX;

    // ---- staging map: exactly one float4 per thread per stage
    // tid -> (scc = tid/144, srr = (tid%144)/6, sseg = tid%6)
    const int scc  = tid / (WROWS * SEGS);
    const int srm  = tid - scc * (WROWS * SEGS);
    const int srr  = srm / SEGS;
    const int sseg = srm - srr * SEGS;
    const int sgy  = y0 - 4 + srr;
    const int sgx  = x0 - 4 + sseg * 4;          // mult of 4 -> seg all-in or all-out of [0,W)
    const bool sval = (sgy >= 0) && (sgy < Hn) && (sgx >= 0) && (sgx < Wn);
    const int slidx = (scc * F1C + srr * LROW + sseg * 4) >> 2;   // float4 index
    const int sgidx = sval ? ((((b * Cn + scc) * Hn + sgy) * Wn + sgx) >> 2) : 0;

    const float4* __restrict__ f1v = (const float4*)f1;
    float4* lv = (float4*)lds;

    // ---- prologue: prefetch stage 0 (f1 window vals + f0 pixels)
    float4 p1 = make_float4(0.f, 0.f, 0.f, 0.f);
    if (sval) p1 = f1v[sgidx];

    const float* f0s = f0 + ((b * Cn) * Hn + y0 + r) * Wn + x0 + g * 4;
    float4 p0[CCH];
#pragma unroll
    for (int cc = 0; cc < CCH; ++cc) p0[cc] = *(const float4*)(f0s + cc * HWn);

    float acc[9][4];
#pragma unroll
    for (int i = 0; i < 9; ++i)
#pragma unroll
        for (int j = 0; j < 4; ++j) acc[i][j] = 0.f;

    for (int s = 0; s < NSTAGE; ++s) {
        // publish this stage's f1 to LDS buffer (s&1)
        lv[(s & 1) * (CCH * F1C / 4) + slidx] = p1;
        __syncthreads();   // the ONLY barrier per stage (see buffer-parity proof in journal)

        // issue next-stage prefetch; stays in flight during compute
        const int ns = (s + 1 < NSTAGE) ? s + 1 : NSTAGE - 1;
        float4 n1 = make_float4(0.f, 0.f, 0.f, 0.f);
        if (sval) n1 = f1v[sgidx + ns * F1CHUNK4];
        float4 n0[CCH];
#pragma unroll
        for (int cc = 0; cc < CCH; ++cc)
            n0[cc] = *(const float4*)(f0s + (ns * CCH + cc) * HWn);

        // compute stage s from LDS buffer (s&1) + f0 regs
        const float* base = &lds[(s & 1) * (CCH * F1C) + (r + wave) * LROW + g * 4];
#pragma unroll
        for (int cc = 0; cc < CCH; ++cc) {
            const float* wr = base + cc * F1C;
            float4 w0 = *(const float4*)(wr);
            float4 w1 = *(const float4*)(wr + 4);
            float4 w2 = *(const float4*)(wr + 8);
            float av[4]  = {p0[cc].x, p0[cc].y, p0[cc].z, p0[cc].w};
            float wv[12] = {w0.x, w0.y, w0.z, w0.w, w1.x, w1.y, w1.z, w1.w,
                            w2.x, w2.y, w2.z, w2.w};
#pragma unroll
            for (int dx = 0; dx < 9; ++dx)
#pragma unroll
                for (int rx = 0; rx < 4; ++rx)
                    acc[dx][rx] = fmaf(av[rx], wv[rx + dx], acc[dx][rx]);
        }

        p1 = n1;
#pragma unroll
        for (int cc = 0; cc < CCH; ++cc) p0[cc] = n0[cc];
    }

    // ---- epilogue: exclusive ownership -> plain coalesced float4 stores
    const int orow = ((b * NP + wave * 9) * Hn + y0 + r) * Wn + x0 + g * 4;
#pragma unroll
    for (int dx = 0; dx < 9; ++dx)
        *(float4*)(out + orow + dx * HWn) =
            make_float4(acc[dx][0], acc[dx][1], acc[dx][2], acc[dx][3]);
}

extern "C" void kernel_launch(void* const* d_in, const int* in_sizes, int n_in,
                              void* d_out, int out_size, void* d_ws, size_t ws_size,
                              hipStream_t stream) {
    const float* f0 = (const float*)d_in[0];
    const float* f1 = (const float*)d_in[1];
    float* out = (float*)d_out;
    corr_kernel<<<dim3(240), NT, 0, stream>>>(f0, f1, out);
}

// Round 4
// 182.755 us; speedup vs baseline: 2.5177x; 1.0706x over previous
//
#include <hip/hip_runtime.h>

// SpatialCorrelationSampler: out[b,(dy+4)*9+(dx+4),y,x] =
//   sum_c f0[b,c,y,x]*f1[b,c,y+dy,x+dx], dy,dx in [-4,4], OOB=0.
// B=4 C=256 H=96 W=160 -> out (4,81,96,160) fp32.
//
// R4: R3 (96us) was latency/burst-bound: stage (CCH=4) compute ~650cyc <
// ~900cyc HBM latency + 1180cyc/stage drain; grid 240 = 1 block/CU always.
//   -> CCH=8: 32 stages, compute/stage ~1300cyc/SIMD covers prefetch latency;
//      half the barriers. Depth-1 reg prefetch for both f1 (2 float4/thr) and
//      f0 (8 float4/thr).
//   -> XCD-spatial swizzle (assumes xcd = blockIdx.x % 8 round-robin): each
//      XCD gets a contiguous 3x10-tile half-batch; stage-synchronous neighbor
//      blocks share f1 halo rows/cols in the XCD's 4MB L2 -> FETCH 199->~160MB.
// Wave w owns dy = w-4; 16x16 tile, RX=4, acc[9][4]=36 regs.

#define Bn 4
#define Cn 256
#define Hn 96
#define Wn 160
#define HWn (Hn * Wn)
#define NP 81
#define TY 16
#define TX 16
#define CCH 8                 // channels per stage
#define NSTAGE (Cn / CCH)     // 32
#define WROWS (TY + 8)        // 24
#define SEGS 6                // float4 segments per 24-float row
#define LROW 28               // padded LDS row stride (floats)
#define F1C (WROWS * LROW)    // 672 floats per staged channel
#define BUF (CCH * F1C)       // 5376 floats per LDS buffer
#define NT 576                // 9 waves
#define F1STG (CCH * HWn / 4) // float4 stride between stages in f1

__global__ __launch_bounds__(NT, 2) void corr_kernel(const float* __restrict__ f0,
                                                     const float* __restrict__ f1,
                                                     float* __restrict__ out) {
    __shared__ __align__(16) float lds[2 * BUF];  // 43008 B double buffer

    const int tid  = threadIdx.x;
    const int wave = tid >> 6;      // 0..8 (dy = wave-4)
    const int lane = tid & 63;
    const int r    = lane >> 2;     // 0..15 tile row
    const int g    = lane & 3;      // 0..3  col group of 4 px

    // XCD-spatial swizzle: 240 blocks = 8 XCDs x 30 tiles (half-batch each).
    const int blk = blockIdx.x;
    const int xcd = blk & 7;
    const int it  = blk >> 3;           // 0..29
    const int b   = xcd >> 1;
    const int ty  = (xcd & 1) * 3 + it / 10;
    const int tx  = it % 10;
    const int y0  = ty * TY;
    const int x0  = tx * TX;

    // ---- staging map: 2 float4/thread/stage; copy 2 = same spot, channel +4
    const int scc  = tid / (WROWS * SEGS);        // 0..3
    const int srm  = tid - scc * (WROWS * SEGS);
    const int srr  = srm / SEGS;
    const int sseg = srm - srr * SEGS;
    const int sgy  = y0 - 4 + srr;
    const int sgx  = x0 - 4 + sseg * 4;           // mult of 4 -> seg all-in/out of [0,W)
    const bool sval = (sgy >= 0) && (sgy < Hn) && (sgx >= 0) && (sgx < Wn);
    const int slidx = (scc * F1C + srr * LROW + sseg * 4) >> 2;   // float4 idx
    const int sgidx = sval ? ((((b * Cn + scc) * Hn + sgy) * Wn + sgx) >> 2) : 0;

    const float4* __restrict__ f1v = (const float4*)f1;
    float4* lv = (float4*)lds;

    // ---- prologue: prefetch stage 0
    float4 p1a = make_float4(0.f, 0.f, 0.f, 0.f), p1b = p1a;
    if (sval) { p1a = f1v[sgidx]; p1b = f1v[sgidx + HWn]; }   // ch scc, scc+4

    const float* f0s = f0 + ((b * Cn) * Hn + y0 + r) * Wn + x0 + g * 4;
    float4 p0[CCH];
#pragma unroll
    for (int cc = 0; cc < CCH; ++cc) p0[cc] = *(const float4*)(f0s + cc * HWn);

    float acc[9][4];
#pragma unroll
    for (int i = 0; i < 9; ++i)
#pragma unroll
        for (int j = 0; j < 4; ++j) acc[i][j] = 0.f;

    for (int s = 0; s < NSTAGE; ++s) {
        // publish stage s's f1 to buffer (s&1); safe vs compute s-2 (same
        // parity) via barrier at s-1; compute s reads after this barrier.
        float4* buf = lv + (s & 1) * (BUF / 4);
        buf[slidx]       = p1a;
        buf[slidx + F1C] = p1b;       // channel +4 -> +4*F1C floats = +F1C float4
        __syncthreads();              // single barrier per stage

        // depth-1 prefetch for stage s+1: in flight across the whole compute
        const int ns = (s + 1 < NSTAGE) ? s + 1 : NSTAGE - 1;
        float4 n1a = make_float4(0.f, 0.f, 0.f, 0.f), n1b = n1a;
        if (sval) { n1a = f1v[sgidx + ns * F1STG]; n1b = f1v[sgidx + ns * F1STG + HWn]; }
        float4 n0[CCH];
#pragma unroll
        for (int cc = 0; cc < CCH; ++cc)
            n0[cc] = *(const float4*)(f0s + (ns * CCH + cc) * HWn);

        // compute stage s
        const float* base = &lds[(s & 1) * BUF + (r + wave) * LROW + g * 4];
#pragma unroll
        for (int cc = 0; cc < CCH; ++cc) {
            const float* wr = base + cc * F1C;
            float4 w0 = *(const float4*)(wr);
            float4 w1 = *(const float4*)(wr + 4);
            float4 w2 = *(const float4*)(wr + 8);
            float av[4]  = {p0[cc].x, p0[cc].y, p0[cc].z, p0[cc].w};
            float wv[12] = {w0.x, w0.y, w0.z, w0.w, w1.x, w1.y, w1.z, w1.w,
                            w2.x, w2.y, w2.z, w2.w};
#pragma unroll
            for (int dx = 0; dx < 9; ++dx)
#pragma unroll
                for (int rx = 0; rx < 4; ++rx)
                    acc[dx][rx] = fmaf(av[rx], wv[rx + dx], acc[dx][rx]);
        }

        p1a = n1a; p1b = n1b;
#pragma unroll
        for (int cc = 0; cc < CCH; ++cc) p0[cc] = n0[cc];
    }

    // ---- epilogue: exclusive ownership -> plain coalesced float4 stores
    const int orow = ((b * NP + wave * 9) * Hn + y0 + r) * Wn + x0 + g * 4;
#pragma unroll
    for (int dx = 0; dx < 9; ++dx)
        *(float4*)(out + orow + dx * HWn) =
            make_float4(acc[dx][0], acc[dx][1], acc[dx][2], acc[dx][3]);
}

extern "C" void kernel_launch(void* const* d_in, const int* in_sizes, int n_in,
                              void* d_out, int out_size, void* d_ws, size_t ws_size,
                              hipStream_t stream) {
    const float* f0 = (const float*)d_in[0];
    const float* f1 = (const float*)d_in[1];
    float* out = (float*)d_out;
    corr_kernel<<<dim3(240), NT, 0, stream>>>(f0, f1, out);
}